// Round 15
// baseline (132.303 us; speedup 1.0000x reference)
//
#include <hip/hip_runtime.h>
#include <float.h>

// VectorQuantizer: x [64,64,32,32] f32, weight [1024,64] f32
// out[n] = weight[argmin_k ||x_n - w_k||^2]
// score = 0.5||w||^2 + (-x).w via split-bf16 MFMA, K=256 FULL product.
// R15 = R14 + staging swapped from global_load_lds DMA to the untested cell:
// global->VGPR->ds_write DOUBLE-buffered (loads for ch+1 issue at top of
// compute phase ch -> latency hidden in regs; barrier drains only lgkm).
// R3 (VGPR staging, single-buf, worse fold) = 49.5us beat all DMA variants.
// Fold: vid in low-5 mantissa bits + med3/min (3 ops); exact lex epilogue;
// inline exact rescue; parallel one-wave-per-code prep.
// NOTE: no pointer ARRAYS into LDS (addrspacecast static-init fails on gfx950).
#define NLAT   65536
#define KCODES 1024
#define DIM    64
#define HW     1024
#define LPB    128
#define CPK    128
#define NCHUNK 8
#define XROW   136          // XE padded row (shorts): 272 B

typedef float f32x4 __attribute__((ext_vector_type(4)));
typedef short short8 __attribute__((ext_vector_type(8)));

static __device__ __forceinline__ unsigned short f2bf(float f) {
    unsigned int u = __float_as_uint(f);
    return (unsigned short)((u + 0x7fffu + ((u >> 16) & 1u)) >> 16);   // RNE
}
static __device__ __forceinline__ float bf2f(unsigned short h) {
    return __uint_as_float(((unsigned int)h) << 16);
}

// ---------------------------------------------------------------------------
// Prep: one WAVE per code (grid 256 x 256 thr). Lane d loads w[k][d]
// (coalesced), shuffle-reduces the norm, writes hi/lo shorts into the
// XOR-swizzled row: logical seg L (L<8: hi, L>=8: lo), phys = L ^ (k & 15).
__global__ __launch_bounds__(256)
void vq_prep(const float* __restrict__ w, unsigned short* __restrict__ WEg,
             float* __restrict__ wn) {
    const int wave = threadIdx.x >> 6, lane = threadIdx.x & 63;
    const int k = blockIdx.x * 4 + wave;
    float v = w[(size_t)k * DIM + lane];
    float s = v * v;
    #pragma unroll
    for (int m = 32; m > 0; m >>= 1) s += __shfl_xor(s, m, 64);
    if (lane == 0) wn[k] = 0.5f * s;
    unsigned short h = f2bf(v);
    unsigned short l = f2bf(v - bf2f(h));
    unsigned short* row = WEg + (size_t)k * 128;
    const int j = lane & 7, Lh = lane >> 3, Ll = 8 + (lane >> 3);
    row[(((Lh ^ (k & 15)) << 3) | j)] = h;
    row[(((Ll ^ (k & 15)) << 3) | j)] = l;
}

// ---------------------------------------------------------------------------
// Main: 512 blocks x 256 thr (2 latent-halves x 2 code-halves). Wave tile
// 64 lats x 64 codes per 128-code chunk; A-frags (negated x) pinned in regs;
// B staged global->VGPR->LDS, double-buffered; inline exact rescue; gather.
__global__ __launch_bounds__(256, 2)
void vq_main(const float* __restrict__ x, const float* __restrict__ w,
             const unsigned short* __restrict__ WEg, const float* __restrict__ wn,
             float* __restrict__ out) {
    __shared__ __align__(16) char smem[66576];
    unsigned short* XE = (unsigned short*)smem;        // [128][136] (phase 0 only)
    char* wbuf0 = smem;                                // 32KB B buf (even chunks)
    char* wbuf1 = smem + 32768;                        // 32KB B buf (odd chunks)
    float* red  = (float*)smem;                        // [32][129] f32 (post-K)
    int*   redk = (int*)(smem + 16512);                // [32][129] int (post-K)
    float* hb1  = (float*)(smem + 33024);              // [2][128] half-reduced score
    int*   hbk  = (int*)(smem + 34048);                // [2][128] half-reduced k
    int*   bfin = (int*)(smem + 65536);                // [128] winner k
    int*   amb  = (int*)(smem + 66048);                // [128] ambiguous lat ids
    int*   ambn = (int*)(smem + 66560);                // count

    const int tid  = threadIdx.x;
    const int wave = tid >> 6, lane = tid & 63;
    const int r16  = lane & 15, quad = lane >> 4;
    const int LH = wave & 1, CH = wave >> 1;

    const int blk = blockIdx.x;
    const int b   = blk >> 3;
    const int hw0 = (blk & 7) * LPB;

    if (tid == 0) ambn[0] = 0;

    // Issue chunk-0 staging loads FIRST (into regs; overlap the x conversion)
    const char* gbase = (const char*)WEg + wave * 8192 + lane * 16;
    int4 g[8];
    #pragma unroll
    for (int i = 0; i < 8; ++i) g[i] = *(const int4*)(gbase + i * 1024);

    // Phase 0: convert NEGATED x tile -> XE[lat][hi 0..63 | lo 64..127]
    {
        const int lat  = tid & 127;
        const int half = tid >> 7;
        const float* xb = x + (size_t)b * (DIM * HW) + hw0 + lat;
        #pragma unroll 8
        for (int c = 0; c < 32; ++c) {
            int chn = half * 32 + c;
            float v = -xb[chn * HW];          // negate: score = wn + (-x).w
            unsigned short h = f2bf(v);
            XE[lat * XROW + chn]      = h;
            XE[lat * XROW + 64 + chn] = f2bf(v - bf2f(h));
        }
    }
    __syncthreads();

    // A-frags: span 0=hi d0-31, 1=hi d32-63, 2=lo d0-31, 3=lo d32-63
    short8 areg[4][4];
    #pragma unroll
    for (int lt = 0; lt < 4; ++lt)
        #pragma unroll
        for (int p = 0; p < 4; ++p)
            areg[lt][p] = *(const short8*)&XE[(LH * 64 + lt * 16 + r16) * XROW + p * 32 + quad * 8];
    __syncthreads();   // XE dead -> wbuf may overwrite

    // Deposit chunk 0 (loads issued at kernel top -> long since returned)
    {
        char* ldst = wbuf0 + wave * 8192 + lane * 16;
        #pragma unroll
        for (int i = 0; i < 8; ++i) *(int4*)(ldst + i * 1024) = g[i];
    }

    float b1[16], b2[16];
    #pragma unroll
    for (int sl = 0; sl < 16; ++sl) { b1[sl] = FLT_MAX; b2[sl] = FLT_MAX; }

    for (int ch = 0; ch < NCHUNK; ++ch) {
        __syncthreads();   // drains ds_writes of chunk ch (lgkm only)
        if (ch + 1 < NCHUNK) {   // issue next chunk's global loads NOW
            const char* gsrc = gbase + (ch + 1) * 32768;
            #pragma unroll
            for (int i = 0; i < 8; ++i) g[i] = *(const int4*)(gsrc + i * 1024);
        }
        const char* cbuf = (ch & 1) ? wbuf1 : wbuf0;
        const int kb = ch * CPK;

        float wnv[4];
        #pragma unroll
        for (int ct = 0; ct < 4; ++ct)
            wnv[ct] = wn[kb + CH * 64 + ct * 16 + r16];
        f32x4 acc[4][4];
        #pragma unroll
        for (int lt = 0; lt < 4; ++lt)
            #pragma unroll
            for (int ct = 0; ct < 4; ++ct) {
                acc[lt][ct][0] = wnv[ct]; acc[lt][ct][1] = wnv[ct];
                acc[lt][ct][2] = wnv[ct]; acc[lt][ct][3] = wnv[ct];
            }

        // K=256 FULL product: spans 0=hi0,1=hi1,2=lo0,3=lo1; each W-span
        // loaded once, used by 2 A-spans: W0(A0,A2) W1(A1,A3) W2(A0,A2) W3(A1,A3)
        const int AI[8]  = {0, 2, 1, 3, 0, 2, 1, 3};
        const int WSp[8] = {0, 0, 1, 1, 2, 2, 3, 3};
        short8 bf[4];
        #pragma unroll
        for (int s = 0; s < 8; ++s) {
            if (s == 0 || WSp[s] != WSp[s - 1]) {
                #pragma unroll
                for (int ct = 0; ct < 4; ++ct) {
                    int r = CH * 64 + ct * 16 + r16;
                    int seg = (WSp[s] * 4 + quad) ^ r16;   // matches prep swizzle
                    bf[ct] = *(const short8*)(cbuf + r * 256 + seg * 16);
                }
            }
            #pragma unroll
            for (int lt = 0; lt < 4; ++lt)
                #pragma unroll
                for (int ct = 0; ct < 4; ++ct)
                    acc[lt][ct] = __builtin_amdgcn_mfma_f32_16x16x32_bf16(
                        areg[lt][AI[s]], bf[ct], acc[lt][ct], 0, 0, 0);
        }

        // Fold (3 ops/score): pack vid; b2 = med3(b1,b2,p); b1 = min(b1,p).
        #pragma unroll
        for (int ct = 0; ct < 4; ++ct) {
            const unsigned vid = (unsigned)((ch << 2) | ct);
            #pragma unroll
            for (int lt = 0; lt < 4; ++lt)
                #pragma unroll
                for (int r = 0; r < 4; ++r) {
                    int sl = lt * 4 + r;
                    float p = __uint_as_float(
                        (__float_as_uint(acc[lt][ct][r]) & 0xFFFFFFE0u) | vid);
                    b2[sl] = __builtin_amdgcn_fmed3f(b1[sl], b2[sl], p);
                    b1[sl] = fminf(b1[sl], p);
                }
        }

        // Deposit next chunk into the other buffer (loads long in flight)
        if (ch + 1 < NCHUNK) {
            char* ldst = (((ch + 1) & 1) ? wbuf1 : wbuf0) + wave * 8192 + lane * 16;
            #pragma unroll
            for (int i = 0; i < 8; ++i) *(int4*)(ldst + i * 1024) = g[i];
        }
    }

    // ---- Epilogue phase 1: exact lexicographic (score,k) reduction ----
    __syncthreads();   // wbuf dead -> red/redk alias safe
    const int cid = CH * 16 + r16;   // 32 contributors per latent
    int kslot[16];
    #pragma unroll
    for (int lt = 0; lt < 4; ++lt)
        #pragma unroll
        for (int r = 0; r < 4; ++r) {
            int sl = lt * 4 + r;
            unsigned ub = __float_as_uint(b1[sl]);
            int vid = (int)(ub & 31u);
            int k = (vid >> 2) * 128 + CH * 64 + (vid & 3) * 16 + r16;
            kslot[sl] = k;
            int lat = LH * 64 + lt * 16 + quad * 4 + r;
            red[cid * 129 + lat]  = __uint_as_float(ub & 0xFFFFFFE0u);
            redk[cid * 129 + lat] = k;
        }
    __syncthreads();
    // 2x-parallel: all 256 threads reduce 16 contributors each
    {
        const int lat = tid & 127, hf = tid >> 7;
        float s1 = red[(hf * 16) * 129 + lat]; int i1 = redk[(hf * 16) * 129 + lat];
        #pragma unroll 4
        for (int c = 1; c < 16; ++c) {
            float s = red[(hf * 16 + c) * 129 + lat];
            int  k2 = redk[(hf * 16 + c) * 129 + lat];
            if (s < s1 || (s == s1 && k2 < i1)) { s1 = s; i1 = k2; }
        }
        hb1[hf * 128 + lat] = s1; hbk[hf * 128 + lat] = i1;
    }
    __syncthreads();
    float B1 = 0.f;
    if (tid < LPB) {
        float sA = hb1[tid];       int kA = hbk[tid];
        float sB = hb1[128 + tid]; int kB = hbk[128 + tid];
        if (sB < sA || (sB == sA && kB < kA)) { sA = sB; kA = kB; }
        B1 = sA; bfin[tid] = kA;
    }
    __syncthreads();
    // Phase 2: global 2nd best = min over (holder-of-winner-k ? b2 : b1)
    #pragma unroll
    for (int lt = 0; lt < 4; ++lt)
        #pragma unroll
        for (int r = 0; r < 4; ++r) {
            int sl = lt * 4 + r;
            int lat = LH * 64 + lt * 16 + quad * 4 + r;
            float b1c = __uint_as_float(__float_as_uint(b1[sl]) & 0xFFFFFFE0u);
            float b2c = __uint_as_float(__float_as_uint(b2[sl]) & 0xFFFFFFE0u);
            red[cid * 129 + lat] = (kslot[sl] == bfin[lat]) ? b2c : b1c;
        }
    __syncthreads();
    {
        const int lat = tid & 127, hf = tid >> 7;
        float m = red[(hf * 16) * 129 + lat];
        #pragma unroll 4
        for (int c = 1; c < 16; ++c) m = fminf(m, red[(hf * 16 + c) * 129 + lat]);
        hb1[hf * 128 + lat] = m;
    }
    __syncthreads();
    if (tid < LPB) {
        float f2 = fminf(hb1[tid], hb1[128 + tid]);
        // eps: split double-rounding residual + fp32 accum + 2x 5-bit vid
        // truncation (2*2^-18 rel). Full product => no dropped-term 1e-3.
        float eps = 4.0e-4f + 4.0e-5f * fabsf(B1);
        if (f2 - B1 < eps) {
            int pos = atomicAdd(ambn, 1);
            amb[pos] = tid;
        }
    }
    __syncthreads();

    // ---- Inline exact rescue: one wave per ambiguous latent ----
    {
        const int na = ambn[0];
        for (int e = wave; e < na; e += 4) {
            const int lat = amb[e];
            const float* xp = x + (size_t)b * (DIM * HW) + hw0 + lat;
            float xs[DIM];
            #pragma unroll
            for (int d = 0; d < DIM; ++d) xs[d] = xp[d * HW];  // wave-uniform
            float bb = FLT_MAX; int bi = 0;
            #pragma unroll 2
            for (int c = 0; c < 16; ++c) {
                int k = c * 64 + lane;
                const float4* wr = (const float4*)(w + (size_t)k * DIM);
                float a0 = 0.f, a1 = 0.f, a2 = 0.f, a3 = 0.f;
                #pragma unroll
                for (int j = 0; j < 16; ++j) {
                    float4 v = wr[j];
                    a0 += xs[4 * j]     * v.x;  a1 += xs[4 * j + 1] * v.y;
                    a2 += xs[4 * j + 2] * v.z;  a3 += xs[4 * j + 3] * v.w;
                }
                float s = wn[k] - ((a0 + a1) + (a2 + a3));
                if (s < bb) { bb = s; bi = k; }
            }
            #pragma unroll
            for (int off = 32; off > 0; off >>= 1) {   // lex (score,k) argmin
                float ob = __shfl_down(bb, off);
                int   oi = __shfl_down(bi, off);
                if (ob < bb || (ob == bb && oi < bi)) { bb = ob; bi = oi; }
            }
            if (lane == 0) bfin[lat] = bi;
        }
    }
    __syncthreads();

    // ---- Gather: out[n][:] = w[bfin][:]  (coalesced float4) ----
    float* outp = out + (size_t)blk * (LPB * DIM);
    #pragma unroll
    for (int r = 0; r < 8; ++r) {
        int idx = r * 256 + tid;
        int row = idx >> 4, seg = idx & 15;
        int code = bfin[row];
        *(float4*)&outp[idx * 4] = *(const float4*)&w[(size_t)code * DIM + seg * 4];
    }
}

extern "C" void kernel_launch(void* const* d_in, const int* in_sizes, int n_in,
                              void* d_out, int out_size, void* d_ws, size_t ws_size,
                              hipStream_t stream) {
    const float* x = (const float*)d_in[0];
    const float* w = (const float*)d_in[1];
    float* out = (float*)d_out;
    unsigned short* WEg = (unsigned short*)d_ws;                  // 262144 B (swizzled)
    float* wn = (float*)((char*)d_ws + 262144);                   // 4096 B

    vq_prep<<<KCODES / 4, 256, 0, stream>>>(w, WEg, wn);
    vq_main<<<NLAT / LPB, 256, 0, stream>>>(x, w, WEg, wn, out);
}

// Round 16
// 109.167 us; speedup vs baseline: 1.2119x; 1.2119x over previous
//
#include <hip/hip_runtime.h>
#include <float.h>

// VectorQuantizer: x [64,64,32,32] f32, weight [1024,64] f32
// out[n] = weight[argmin_k ||x_n - w_k||^2]
// score = 0.5||w||^2 + (-x).w via split-bf16 MFMA, K=256 FULL product
// (only fp32-accum + 5-bit-vid truncation error => eps ~4e-4, few rescues).
// FINAL = R14 (best measured: 111.2us total, vq_main 52.5us, no spill).
// Staging matrix fully explored: global_load_lds dbuf (this) = 52.5 clean;
// VGPR-roundtrip dbuf (R15) = 74.6 SPILLS (32 staging VGPRs held across
// MFMA phase -> 80MB scratch); VGPR single (R3) = 49.5 w/ worse fold;
// DMA single (R10) = 58. Occupancy variants (R10/11/12) all regressed:
// kernel is barrier-drain + dep-latency bound (m97-class, m131-m141).
// B staged via global_load_lds double-buffer (prefetch one phase ahead).
// Fold embeds vid=(ch<<2)|ct (5 bits) in score's low mantissa (1 op) +
// med3/min top-2 update (2 ops); exact lex (score,k) epilogue, 2x-parallel;
// ambiguous latents rescored exactly inline (one wave per latent).
// NOTE: no pointer ARRAYS into LDS (addrspacecast static-init fails on gfx950).
#define NLAT   65536
#define KCODES 1024
#define DIM    64
#define HW     1024
#define LPB    128
#define CPK    128
#define NCHUNK 8
#define XROW   136          // XE padded row (shorts): 272 B

typedef float f32x4 __attribute__((ext_vector_type(4)));
typedef short short8 __attribute__((ext_vector_type(8)));

static __device__ __forceinline__ unsigned short f2bf(float f) {
    unsigned int u = __float_as_uint(f);
    return (unsigned short)((u + 0x7fffu + ((u >> 16) & 1u)) >> 16);   // RNE
}
static __device__ __forceinline__ float bf2f(unsigned short h) {
    return __uint_as_float(((unsigned int)h) << 16);
}
static __device__ __forceinline__ void async_cp16(const void* g, void* l) {
    __builtin_amdgcn_global_load_lds(
        (const __attribute__((address_space(1))) unsigned int*)g,
        (__attribute__((address_space(3))) unsigned int*)l, 16, 0, 0);
}

// ---------------------------------------------------------------------------
// Prep: one WAVE per code (grid 256 x 256 thr). Lane d loads w[k][d]
// (coalesced), shuffle-reduces the norm, writes hi/lo shorts into the
// XOR-swizzled row: logical seg L (L<8: hi, L>=8: lo), phys = L ^ (k & 15).
__global__ __launch_bounds__(256)
void vq_prep(const float* __restrict__ w, unsigned short* __restrict__ WEg,
             float* __restrict__ wn) {
    const int wave = threadIdx.x >> 6, lane = threadIdx.x & 63;
    const int k = blockIdx.x * 4 + wave;
    float v = w[(size_t)k * DIM + lane];
    float s = v * v;
    #pragma unroll
    for (int m = 32; m > 0; m >>= 1) s += __shfl_xor(s, m, 64);
    if (lane == 0) wn[k] = 0.5f * s;
    unsigned short h = f2bf(v);
    unsigned short l = f2bf(v - bf2f(h));
    unsigned short* row = WEg + (size_t)k * 128;
    const int j = lane & 7, Lh = lane >> 3, Ll = 8 + (lane >> 3);
    row[(((Lh ^ (k & 15)) << 3) | j)] = h;
    row[(((Ll ^ (k & 15)) << 3) | j)] = l;
}

// ---------------------------------------------------------------------------
// Main: 512 blocks x 256 thr (2 latent-halves x 2 code-halves). Wave tile
// 64 lats x 64 codes per 128-code chunk; A-frags (negated x) pinned in regs;
// B double-buffered in LDS via async DMA; inline exact rescue; gather.
__global__ __launch_bounds__(256, 2)
void vq_main(const float* __restrict__ x, const float* __restrict__ w,
             const unsigned short* __restrict__ WEg, const float* __restrict__ wn,
             float* __restrict__ out) {
    __shared__ __align__(16) char smem[66576];
    unsigned short* XE = (unsigned short*)smem;        // [128][136] (phase 0 only)
    char* wbuf0 = smem;                                // 32KB B buf (even chunks)
    char* wbuf1 = smem + 32768;                        // 32KB B buf (odd chunks)
    float* red  = (float*)smem;                        // [32][129] f32 (post-K)
    int*   redk = (int*)(smem + 16512);                // [32][129] int (post-K)
    float* hb1  = (float*)(smem + 33024);              // [2][128] half-reduced score
    int*   hbk  = (int*)(smem + 34048);                // [2][128] half-reduced k
    int*   bfin = (int*)(smem + 65536);                // [128] winner k
    int*   amb  = (int*)(smem + 66048);                // [128] ambiguous lat ids
    int*   ambn = (int*)(smem + 66560);                // count

    const int tid  = threadIdx.x;
    const int wave = tid >> 6, lane = tid & 63;
    const int r16  = lane & 15, quad = lane >> 4;
    const int LH = wave & 1, CH = wave >> 1;

    const int blk = blockIdx.x;
    const int b   = blk >> 3;
    const int hw0 = (blk & 7) * LPB;

    if (tid == 0) ambn[0] = 0;

    // Phase 0: convert NEGATED x tile -> XE[lat][hi 0..63 | lo 64..127]
    {
        const int lat  = tid & 127;
        const int half = tid >> 7;
        const float* xb = x + (size_t)b * (DIM * HW) + hw0 + lat;
        #pragma unroll 8
        for (int c = 0; c < 32; ++c) {
            int chn = half * 32 + c;
            float v = -xb[chn * HW];          // negate: score = wn + (-x).w
            unsigned short h = f2bf(v);
            XE[lat * XROW + chn]      = h;
            XE[lat * XROW + 64 + chn] = f2bf(v - bf2f(h));
        }
    }
    __syncthreads();

    // A-frags: span 0=hi d0-31, 1=hi d32-63, 2=lo d0-31, 3=lo d32-63
    short8 areg[4][4];
    #pragma unroll
    for (int lt = 0; lt < 4; ++lt)
        #pragma unroll
        for (int p = 0; p < 4; ++p)
            areg[lt][p] = *(const short8*)&XE[(LH * 64 + lt * 16 + r16) * XROW + p * 32 + quad * 8];
    __syncthreads();   // XE dead -> wbuf may overwrite

    // Prefetch chunk 0 into wbuf0 (drained by the first loop-top barrier)
    {
        const char* gsrc = (const char*)WEg + wave * 8192 + lane * 16;
        char* ldst = wbuf0 + wave * 8192;
        #pragma unroll
        for (int i = 0; i < 8; ++i) async_cp16(gsrc + i * 1024, ldst + i * 1024);
    }

    float b1[16], b2[16];
    #pragma unroll
    for (int sl = 0; sl < 16; ++sl) { b1[sl] = FLT_MAX; b2[sl] = FLT_MAX; }

    for (int ch = 0; ch < NCHUNK; ++ch) {
        __syncthreads();   // drains chunk-ch DMA (issued one full phase ago)
        if (ch + 1 < NCHUNK) {   // prefetch next chunk into the other buffer
            const char* gsrc = (const char*)WEg + (ch + 1) * 32768 + wave * 8192 + lane * 16;
            char* ldst = (((ch + 1) & 1) ? wbuf1 : wbuf0) + wave * 8192;
            #pragma unroll
            for (int i = 0; i < 8; ++i) async_cp16(gsrc + i * 1024, ldst + i * 1024);
        }
        const char* cbuf = (ch & 1) ? wbuf1 : wbuf0;
        const int kb = ch * CPK;

        float wnv[4];
        #pragma unroll
        for (int ct = 0; ct < 4; ++ct)
            wnv[ct] = wn[kb + CH * 64 + ct * 16 + r16];
        f32x4 acc[4][4];
        #pragma unroll
        for (int lt = 0; lt < 4; ++lt)
            #pragma unroll
            for (int ct = 0; ct < 4; ++ct) {
                acc[lt][ct][0] = wnv[ct]; acc[lt][ct][1] = wnv[ct];
                acc[lt][ct][2] = wnv[ct]; acc[lt][ct][3] = wnv[ct];
            }

        // K=256 FULL product: spans 0=hi0,1=hi1,2=lo0,3=lo1; each W-span
        // loaded once, used by 2 A-spans: W0(A0,A2) W1(A1,A3) W2(A0,A2) W3(A1,A3)
        const int AI[8]  = {0, 2, 1, 3, 0, 2, 1, 3};
        const int WSp[8] = {0, 0, 1, 1, 2, 2, 3, 3};
        short8 bf[4];
        #pragma unroll
        for (int s = 0; s < 8; ++s) {
            if (s == 0 || WSp[s] != WSp[s - 1]) {
                #pragma unroll
                for (int ct = 0; ct < 4; ++ct) {
                    int r = CH * 64 + ct * 16 + r16;
                    int seg = (WSp[s] * 4 + quad) ^ r16;   // matches prep swizzle
                    bf[ct] = *(const short8*)(cbuf + r * 256 + seg * 16);
                }
            }
            #pragma unroll
            for (int lt = 0; lt < 4; ++lt)
                #pragma unroll
                for (int ct = 0; ct < 4; ++ct)
                    acc[lt][ct] = __builtin_amdgcn_mfma_f32_16x16x32_bf16(
                        areg[lt][AI[s]], bf[ct], acc[lt][ct], 0, 0, 0);
        }

        // Fold (3 ops/score): pack vid; b2 = med3(b1,b2,p) (exact top-2
        // update: p<b1 -> b1; b1<=p<=b2 -> p; p>b2 -> b2); b1 = min(b1,p).
        // Distinct vids => no exact-equal hazard.
        #pragma unroll
        for (int ct = 0; ct < 4; ++ct) {
            const unsigned vid = (unsigned)((ch << 2) | ct);
            #pragma unroll
            for (int lt = 0; lt < 4; ++lt)
                #pragma unroll
                for (int r = 0; r < 4; ++r) {
                    int sl = lt * 4 + r;
                    float p = __uint_as_float(
                        (__float_as_uint(acc[lt][ct][r]) & 0xFFFFFFE0u) | vid);
                    b2[sl] = __builtin_amdgcn_fmed3f(b1[sl], b2[sl], p);
                    b1[sl] = fminf(b1[sl], p);
                }
        }
    }

    // ---- Epilogue phase 1: exact lexicographic (score,k) reduction ----
    __syncthreads();   // wbuf dead -> red/redk alias safe
    const int cid = CH * 16 + r16;   // 32 contributors per latent
    int kslot[16];
    #pragma unroll
    for (int lt = 0; lt < 4; ++lt)
        #pragma unroll
        for (int r = 0; r < 4; ++r) {
            int sl = lt * 4 + r;
            unsigned ub = __float_as_uint(b1[sl]);
            int vid = (int)(ub & 31u);
            int k = (vid >> 2) * 128 + CH * 64 + (vid & 3) * 16 + r16;
            kslot[sl] = k;
            int lat = LH * 64 + lt * 16 + quad * 4 + r;
            red[cid * 129 + lat]  = __uint_as_float(ub & 0xFFFFFFE0u);
            redk[cid * 129 + lat] = k;
        }
    __syncthreads();
    // 2x-parallel: all 256 threads reduce 16 contributors each
    {
        const int lat = tid & 127, hf = tid >> 7;
        float s1 = red[(hf * 16) * 129 + lat]; int i1 = redk[(hf * 16) * 129 + lat];
        #pragma unroll 4
        for (int c = 1; c < 16; ++c) {
            float s = red[(hf * 16 + c) * 129 + lat];
            int  k2 = redk[(hf * 16 + c) * 129 + lat];
            if (s < s1 || (s == s1 && k2 < i1)) { s1 = s; i1 = k2; }
        }
        hb1[hf * 128 + lat] = s1; hbk[hf * 128 + lat] = i1;
    }
    __syncthreads();
    float B1 = 0.f;
    if (tid < LPB) {
        float sA = hb1[tid];       int kA = hbk[tid];
        float sB = hb1[128 + tid]; int kB = hbk[128 + tid];
        if (sB < sA || (sB == sA && kB < kA)) { sA = sB; kA = kB; }
        B1 = sA; bfin[tid] = kA;
    }
    __syncthreads();
    // Phase 2: global 2nd best = min over (holder-of-winner-k ? b2 : b1)
    #pragma unroll
    for (int lt = 0; lt < 4; ++lt)
        #pragma unroll
        for (int r = 0; r < 4; ++r) {
            int sl = lt * 4 + r;
            int lat = LH * 64 + lt * 16 + quad * 4 + r;
            float b1c = __uint_as_float(__float_as_uint(b1[sl]) & 0xFFFFFFE0u);
            float b2c = __uint_as_float(__float_as_uint(b2[sl]) & 0xFFFFFFE0u);
            red[cid * 129 + lat] = (kslot[sl] == bfin[lat]) ? b2c : b1c;
        }
    __syncthreads();
    {
        const int lat = tid & 127, hf = tid >> 7;
        float m = red[(hf * 16) * 129 + lat];
        #pragma unroll 4
        for (int c = 1; c < 16; ++c) m = fminf(m, red[(hf * 16 + c) * 129 + lat]);
        hb1[hf * 128 + lat] = m;
    }
    __syncthreads();
    if (tid < LPB) {
        float f2 = fminf(hb1[tid], hb1[128 + tid]);
        // eps: split double-rounding residual + fp32 accum + 2x 5-bit vid
        // truncation (2*2^-18 rel). Full product => no dropped-term 1e-3.
        float eps = 4.0e-4f + 4.0e-5f * fabsf(B1);
        if (f2 - B1 < eps) {
            int pos = atomicAdd(ambn, 1);
            amb[pos] = tid;
        }
    }
    __syncthreads();

    // ---- Inline exact rescue: one wave per ambiguous latent ----
    {
        const int na = ambn[0];
        for (int e = wave; e < na; e += 4) {
            const int lat = amb[e];
            const float* xp = x + (size_t)b * (DIM * HW) + hw0 + lat;
            float xs[DIM];
            #pragma unroll
            for (int d = 0; d < DIM; ++d) xs[d] = xp[d * HW];  // wave-uniform
            float bb = FLT_MAX; int bi = 0;
            #pragma unroll 2
            for (int c = 0; c < 16; ++c) {
                int k = c * 64 + lane;
                const float4* wr = (const float4*)(w + (size_t)k * DIM);
                float a0 = 0.f, a1 = 0.f, a2 = 0.f, a3 = 0.f;
                #pragma unroll
                for (int j = 0; j < 16; ++j) {
                    float4 v = wr[j];
                    a0 += xs[4 * j]     * v.x;  a1 += xs[4 * j + 1] * v.y;
                    a2 += xs[4 * j + 2] * v.z;  a3 += xs[4 * j + 3] * v.w;
                }
                float s = wn[k] - ((a0 + a1) + (a2 + a3));
                if (s < bb) { bb = s; bi = k; }
            }
            #pragma unroll
            for (int off = 32; off > 0; off >>= 1) {   // lex (score,k) argmin
                float ob = __shfl_down(bb, off);
                int   oi = __shfl_down(bi, off);
                if (ob < bb || (ob == bb && oi < bi)) { bb = ob; bi = oi; }
            }
            if (lane == 0) bfin[lat] = bi;
        }
    }
    __syncthreads();

    // ---- Gather: out[n][:] = w[bfin][:]  (coalesced float4) ----
    float* outp = out + (size_t)blk * (LPB * DIM);
    #pragma unroll
    for (int r = 0; r < 8; ++r) {
        int idx = r * 256 + tid;
        int row = idx >> 4, seg = idx & 15;
        int code = bfin[row];
        *(float4*)&outp[idx * 4] = *(const float4*)&w[(size_t)code * DIM + seg * 4];
    }
}

extern "C" void kernel_launch(void* const* d_in, const int* in_sizes, int n_in,
                              void* d_out, int out_size, void* d_ws, size_t ws_size,
                              hipStream_t stream) {
    const float* x = (const float*)d_in[0];
    const float* w = (const float*)d_in[1];
    float* out = (float*)d_out;
    unsigned short* WEg = (unsigned short*)d_ws;                  // 262144 B (swizzled)
    float* wn = (float*)((char*)d_ws + 262144);                   // 4096 B

    vq_prep<<<KCODES / 4, 256, 0, stream>>>(w, WEg, wn);
    vq_main<<<NLAT / LPB, 256, 0, stream>>>(x, w, WEg, wn, out);
}